// Round 4
// baseline (443.714 us; speedup 1.0000x reference)
//
#include <hip/hip_runtime.h>

// GeometryAttentionBias: out[b,i,j] = exp(-(ci-cj)^2/(2 g^2)) + (ni.nj+1)/2
//                                     - sigma*(di+dj) + li*lj - aniso[b,i,j]
// B=4, N=4096, all f32. Memory-bound streaming kernel:
// read aniso (256 MiB) + write out (256 MiB); per-point data L2-resident.
// Roofline: 512 MiB @ ~6.3 TB/s achievable => ~85 us floor.
//
// R3: dropped nontemporal hints (fill kernel hits 6.4 TB/s with cached
// writes; nt was the one unvalidated path). ROWS 16->8, fully unrolled so
// all 8 stream loads issue before dependent compute (128 B in flight/thread).

constexpr int N_PTS = 4096;
constexpr int COLS_PER_BLOCK = 1024;  // 256 threads x 4 cols
constexpr int ROWS_PER_BLOCK = 8;

typedef float vfloat4 __attribute__((ext_vector_type(4)));

__global__ __launch_bounds__(256) void geo_bias_kernel(
    const float* __restrict__ g_cur,
    const float* __restrict__ g_den,
    const float* __restrict__ g_nrm,
    const float* __restrict__ g_lin,
    const float* __restrict__ g_ani,
    const float* __restrict__ g_gamma,
    const float* __restrict__ g_sigma,
    const float* __restrict__ g_cscale,
    float* __restrict__ g_out)
{
    const int b  = blockIdx.z;
    const int i0 = blockIdx.y * ROWS_PER_BLOCK;
    const int j0 = blockIdx.x * COLS_PER_BLOCK + threadIdx.x * 4;

    const float gamma  = g_gamma[0];
    const float nsig   = -g_sigma[0];
    const float cscale = g_cscale[0];
    // exp(-d^2/(2g^2)) = exp2(d^2 * k), k = -log2(e)/(2g^2)
    const float k = -1.4426950408889634f / (2.0f * gamma * gamma);

    const float* cur = g_cur + (size_t)b * N_PTS;
    const float* den = g_den + (size_t)b * N_PTS;
    const float* lin = g_lin + (size_t)b * N_PTS;
    const float* nrm = g_nrm + (size_t)b * N_PTS * 3;
    const float* ani = g_ani + (size_t)b * N_PTS * N_PTS;
    float*       out = g_out + (size_t)b * N_PTS * N_PTS;

    // ---- column-side (j) data: loaded once, reused for ROWS_PER_BLOCK rows ----
    const vfloat4 cj4 = *reinterpret_cast<const vfloat4*>(cur + j0);
    const vfloat4 dj4 = *reinterpret_cast<const vfloat4*>(den + j0);
    const vfloat4 lj4 = *reinterpret_cast<const vfloat4*>(lin + j0);
    const vfloat4 na = *reinterpret_cast<const vfloat4*>(nrm + (size_t)j0 * 3);
    const vfloat4 nb = *reinterpret_cast<const vfloat4*>(nrm + (size_t)j0 * 3 + 4);
    const vfloat4 nc = *reinterpret_cast<const vfloat4*>(nrm + (size_t)j0 * 3 + 8);

    const float cj[4]  = {cj4.x * cscale, cj4.y * cscale, cj4.z * cscale, cj4.w * cscale};
    const float sdj[4] = {nsig * dj4.x, nsig * dj4.y, nsig * dj4.z, nsig * dj4.w};
    const float lj[4]  = {lj4.x, lj4.y, lj4.z, lj4.w};
    const float njx[4] = {na.x, na.w, nb.z, nc.y};
    const float njy[4] = {na.y, nb.x, nb.w, nc.z};
    const float njz[4] = {na.z, nb.y, nc.x, nc.w};

    // ---- row-side (i) scalars: block-uniform -> scalar loads ----
    float ci_r[ROWS_PER_BLOCK], li_r[ROWS_PER_BLOCK], rowc_r[ROWS_PER_BLOCK];
    float nix_r[ROWS_PER_BLOCK], niy_r[ROWS_PER_BLOCK], niz_r[ROWS_PER_BLOCK];
#pragma unroll
    for (int r = 0; r < ROWS_PER_BLOCK; ++r) {
        const int i = i0 + r;
        ci_r[r]  = cur[i] * cscale;
        li_r[r]  = lin[i];
        nix_r[r] = nrm[(size_t)i * 3 + 0];
        niy_r[r] = nrm[(size_t)i * 3 + 1];
        niz_r[r] = nrm[(size_t)i * 3 + 2];
        rowc_r[r] = nsig * den[i] + 0.5f;  // -sigma*di + 0.5 (norm_cons const)
    }

    // ---- issue ALL stream loads first: 8 x 16 B in flight per thread ----
    vfloat4 a4[ROWS_PER_BLOCK];
#pragma unroll
    for (int r = 0; r < ROWS_PER_BLOCK; ++r) {
        const size_t off = (size_t)(i0 + r) * N_PTS + j0;
        a4[r] = *reinterpret_cast<const vfloat4*>(ani + off);
    }

    // ---- compute + store ----
#pragma unroll
    for (int r = 0; r < ROWS_PER_BLOCK; ++r) {
        const float ci = ci_r[r], li = li_r[r], rowc = rowc_r[r];
        const float nix = nix_r[r], niy = niy_r[r], niz = niz_r[r];
        const float a[4] = {a4[r].x, a4[r].y, a4[r].z, a4[r].w};

        float o[4];
#pragma unroll
        for (int u = 0; u < 4; ++u) {
            const float d   = ci - cj[u];
            const float cs  = exp2f(d * d * k);
            const float dot = nix * njx[u] + niy * njy[u] + niz * njz[u];
            o[u] = cs + 0.5f * dot + (rowc + sdj[u]) + li * lj[u] - a[u];
        }

        vfloat4 o4 = {o[0], o[1], o[2], o[3]};
        const size_t off = (size_t)(i0 + r) * N_PTS + j0;
        *reinterpret_cast<vfloat4*>(out + off) = o4;
    }
}

extern "C" void kernel_launch(void* const* d_in, const int* in_sizes, int n_in,
                              void* d_out, int out_size, void* d_ws, size_t ws_size,
                              hipStream_t stream) {
    const float* cur    = (const float*)d_in[0];
    const float* den    = (const float*)d_in[1];
    const float* nrm    = (const float*)d_in[2];
    const float* lin    = (const float*)d_in[3];
    const float* ani    = (const float*)d_in[4];
    const float* gamma  = (const float*)d_in[5];
    const float* sigma  = (const float*)d_in[6];
    const float* cscale = (const float*)d_in[7];
    float* out = (float*)d_out;

    const int batches = in_sizes[0] / N_PTS;  // B = 4
    dim3 grid(N_PTS / COLS_PER_BLOCK, N_PTS / ROWS_PER_BLOCK, batches);
    dim3 block(256);
    geo_bias_kernel<<<grid, block, 0, stream>>>(cur, den, nrm, lin, ani,
                                                gamma, sigma, cscale, out);
}

// Round 5
// 440.155 us; speedup vs baseline: 1.0081x; 1.0081x over previous
//
#include <hip/hip_runtime.h>

// GeometryAttentionBias: out[b,i,j] = exp(-(ci-cj)^2/(2 g^2)) + (ni.nj+1)/2
//                                     - sigma*(di+dj) + li*lj - aniso[b,i,j]
// B=4, N=4096, all f32. Memory-bound streaming kernel:
// read aniso (256 MiB) + write out (256 MiB); per-point data L2-resident.
// Roofline: 537 MB @ ~6.3 TB/s achievable => ~85 us floor.
//
// R5: occupancy push. __launch_bounds__(256,4) caps VGPR at 128 (4 waves/SIMD,
// 16/CU vs ~2-3 before). Row scalars are blockIdx-uniform -> SGPR path; only
// the 8x float4 stream-prefetch block lives in VGPRs.

constexpr int N_PTS = 4096;
constexpr int COLS_PER_BLOCK = 1024;  // 256 threads x 4 cols
constexpr int ROWS_PER_BLOCK = 8;

typedef float vfloat4 __attribute__((ext_vector_type(4)));

__global__ __launch_bounds__(256, 4) void geo_bias_kernel(
    const float* __restrict__ g_cur,
    const float* __restrict__ g_den,
    const float* __restrict__ g_nrm,
    const float* __restrict__ g_lin,
    const float* __restrict__ g_ani,
    const float* __restrict__ g_gamma,
    const float* __restrict__ g_sigma,
    const float* __restrict__ g_cscale,
    float* __restrict__ g_out)
{
    const int b  = blockIdx.z;
    const int i0 = blockIdx.y * ROWS_PER_BLOCK;
    const int j0 = blockIdx.x * COLS_PER_BLOCK + threadIdx.x * 4;

    const float gamma  = g_gamma[0];
    const float nsig   = -g_sigma[0];
    const float cscale = g_cscale[0];
    // exp(-d^2/(2g^2)) = exp2(d^2 * k), k = -log2(e)/(2g^2)
    const float k = -1.4426950408889634f / (2.0f * gamma * gamma);

    const float* cur = g_cur + (size_t)b * N_PTS;
    const float* den = g_den + (size_t)b * N_PTS;
    const float* lin = g_lin + (size_t)b * N_PTS;
    const float* nrm = g_nrm + (size_t)b * N_PTS * 3;
    const float* ani = g_ani + (size_t)b * N_PTS * N_PTS;
    float*       out = g_out + (size_t)b * N_PTS * N_PTS;

    // ---- issue ALL stream loads first: 8 x 16 B in flight per thread ----
    vfloat4 a4[ROWS_PER_BLOCK];
#pragma unroll
    for (int r = 0; r < ROWS_PER_BLOCK; ++r) {
        const size_t off = (size_t)(i0 + r) * N_PTS + j0;
        a4[r] = *reinterpret_cast<const vfloat4*>(ani + off);
    }

    // ---- column-side (j) data: loaded once, reused for ROWS_PER_BLOCK rows ----
    const vfloat4 cj4 = *reinterpret_cast<const vfloat4*>(cur + j0);
    const vfloat4 dj4 = *reinterpret_cast<const vfloat4*>(den + j0);
    const vfloat4 lj4 = *reinterpret_cast<const vfloat4*>(lin + j0);
    const vfloat4 na = *reinterpret_cast<const vfloat4*>(nrm + (size_t)j0 * 3);
    const vfloat4 nb = *reinterpret_cast<const vfloat4*>(nrm + (size_t)j0 * 3 + 4);
    const vfloat4 nc = *reinterpret_cast<const vfloat4*>(nrm + (size_t)j0 * 3 + 8);

    const float cj[4]  = {cj4.x * cscale, cj4.y * cscale, cj4.z * cscale, cj4.w * cscale};
    const float sdj[4] = {nsig * dj4.x, nsig * dj4.y, nsig * dj4.z, nsig * dj4.w};
    const float lj[4]  = {lj4.x, lj4.y, lj4.z, lj4.w};
    const float njx[4] = {na.x, na.w, nb.z, nc.y};
    const float njy[4] = {na.y, nb.x, nb.w, nc.z};
    const float njz[4] = {na.z, nb.y, nc.x, nc.w};

    // ---- per row: uniform scalars (SGPR path) + compute + store ----
#pragma unroll
    for (int r = 0; r < ROWS_PER_BLOCK; ++r) {
        const int i = i0 + r;
        // blockIdx-uniform -> compiler emits s_loads; no VGPR cost
        const float ci  = cur[i] * cscale;
        const float li  = lin[i];
        const float nix = nrm[(size_t)i * 3 + 0];
        const float niy = nrm[(size_t)i * 3 + 1];
        const float niz = nrm[(size_t)i * 3 + 2];
        const float rowc = nsig * den[i] + 0.5f;  // -sigma*di + 0.5

        const float a[4] = {a4[r].x, a4[r].y, a4[r].z, a4[r].w};
        float o[4];
#pragma unroll
        for (int u = 0; u < 4; ++u) {
            const float d   = ci - cj[u];
            const float cs  = exp2f(d * d * k);
            const float dot = nix * njx[u] + niy * njy[u] + niz * njz[u];
            o[u] = cs + 0.5f * dot + (rowc + sdj[u]) + li * lj[u] - a[u];
        }

        vfloat4 o4 = {o[0], o[1], o[2], o[3]};
        const size_t off = (size_t)i * N_PTS + j0;
        *reinterpret_cast<vfloat4*>(out + off) = o4;
    }
}

extern "C" void kernel_launch(void* const* d_in, const int* in_sizes, int n_in,
                              void* d_out, int out_size, void* d_ws, size_t ws_size,
                              hipStream_t stream) {
    const float* cur    = (const float*)d_in[0];
    const float* den    = (const float*)d_in[1];
    const float* nrm    = (const float*)d_in[2];
    const float* lin    = (const float*)d_in[3];
    const float* ani    = (const float*)d_in[4];
    const float* gamma  = (const float*)d_in[5];
    const float* sigma  = (const float*)d_in[6];
    const float* cscale = (const float*)d_in[7];
    float* out = (float*)d_out;

    const int batches = in_sizes[0] / N_PTS;  // B = 4
    dim3 grid(N_PTS / COLS_PER_BLOCK, N_PTS / ROWS_PER_BLOCK, batches);
    dim3 block(256);
    geo_bias_kernel<<<grid, block, 0, stream>>>(cur, den, nrm, lin, ani,
                                                gamma, sigma, cscale, out);
}